// Round 1
// baseline (318.111 us; speedup 1.0000x reference)
//
#include <hip/hip_runtime.h>

// CostVolume via bf16 MFMA Gram band: cost[b,d,h,w] = (1/64)·G[w][w-d],
// G = L^T·R per (b,h), banded (0 <= d < 48). B=4 C=64 H=256 W=512 D=48.
//
// Round-4 restructure: LDS tiles stored TRANSPOSED ([w][c] rows of 32 bf16 =
// 64 B) so each MFMA fragment (8 consecutive c at one w) is ONE ds_read_b128
// instead of 8 ds_read_u16 column gathers (320 -> 40 LDS reads per lane per
// block). 64-lane b128 column reads at 64 B row stride hit all 32 banks
// uniformly (8 accesses each = the 1 KiB minimum) -- no swizzle needed.
// The global->LDS transpose happens in registers: each thread loads 4
// consecutive c-rows (float4 along w, fully coalesced), repacks into
// (c,c+1)(c+2,c+3) bf16 pairs, writes one b64 per output w. Staging fully
// unrolled so all 8 loads per tile are in flight at once (old rolled loops
// serialized one HBM latency per float4).
// Numerics (f2bf2 RNE + MFMA chunk order) identical to the round-3-verified
// kernel. Epilogue unchanged from round 3: block-wide scratch scatter then
// cooperative full-128B-line nontemporal float4 stores (no write amplif.).

#define BB 4
#define CC 64
#define HH 256
#define WW 512
#define DD 48
#define TW 256
#define CK 32          // channel chunk (= MFMA K)
#define RW 304         // right window cols: w0-48 .. w0+255
#define WR 32          // shorts per LDS row (64 B)
#define ST 257         // epilogue scratch row stride (fp32)
#define NT 256

typedef short bf16x8 __attribute__((ext_vector_type(8)));
typedef float f32x4  __attribute__((ext_vector_type(4)));

// fp32 -> bf16 round-to-nearest-even, packed pair (lo in bits 15:0)
__device__ __forceinline__ unsigned int f2bf2(float lo, float hi) {
  unsigned int a = __float_as_uint(lo);
  unsigned int b = __float_as_uint(hi);
  a = (a + 0x7fffu + ((a >> 16) & 1u)) >> 16;
  b = (b + 0x7fffu + ((b >> 16) & 1u)) & 0xffff0000u;
  return a | b;
}

__global__ __launch_bounds__(NT, 4)
void cost_volume_mfma(const float* __restrict__ left,
                      const float* __restrict__ right,
                      float* __restrict__ out) {
  // (256+304) rows x 64 B = 35840 B; epilogue scratch (24*257*4 = 24672 B)
  // aliases the same region.
  __shared__ __align__(16) char smem[(TW + RW) * WR * 2];
  unsigned short* sL = reinterpret_cast<unsigned short*>(smem);   // [w][c]
  unsigned short* sR = sL + TW * WR;                              // [w'][c]
  float*          scr = reinterpret_cast<float*>(smem);

  const int w0   = blockIdx.x * TW;   // 0 or 256
  const int h    = blockIdx.y;
  const int b    = blockIdx.z;
  const int tid  = threadIdx.x;
  const int lane = tid & 63;
  const int wv   = tid >> 6;          // wave 0..3
  const int n16  = lane & 15;
  const int q    = lane >> 4;

  const size_t HWs   = (size_t)HH * WW;
  const size_t bbase = ((size_t)b * CC) * HWs + (size_t)h * WW;

  // staging assignment: w-quad from low lane bits (coalesced 256B segments),
  // c-quad from high lane bits (4 rows per wave per phase)
  const int wq4 = 4 * ((tid & 15) + 16 * wv);  // 0..252 step 4
  const int cph = 4 * ((tid >> 4) & 3);        // 0,4,8,12

  f32x4 acc[4][4];
  #pragma unroll
  for (int i = 0; i < 4; ++i)
    #pragma unroll
    for (int t = 0; t < 4; ++t)
      acc[i][t] = (f32x4){0.f, 0.f, 0.f, 0.f};

  for (int c0 = 0; c0 < CC; c0 += CK) {
    // ---- stage left tile: [w 0..255][c 0..31], transposed in registers
    {
      f32x4 v[2][4];
      #pragma unroll
      for (int ph = 0; ph < 2; ++ph)
        #pragma unroll
        for (int r = 0; r < 4; ++r)
          v[ph][r] = *reinterpret_cast<const f32x4*>(
              left + bbase + (size_t)(c0 + cph + 16 * ph + r) * HWs + w0 + wq4);
      #pragma unroll
      for (int ph = 0; ph < 2; ++ph)
        #pragma unroll
        for (int j = 0; j < 4; ++j) {
          uint2 pk;
          pk.x = f2bf2(v[ph][0][j], v[ph][1][j]);
          pk.y = f2bf2(v[ph][2][j], v[ph][3][j]);
          *reinterpret_cast<uint2*>(&sL[(wq4 + j) * WR + cph + 16 * ph]) = pk;
        }
    }
    // ---- stage right main part: window cols 48..303 (= w0 .. w0+255)
    {
      f32x4 v[2][4];
      #pragma unroll
      for (int ph = 0; ph < 2; ++ph)
        #pragma unroll
        for (int r = 0; r < 4; ++r)
          v[ph][r] = *reinterpret_cast<const f32x4*>(
              right + bbase + (size_t)(c0 + cph + 16 * ph + r) * HWs + w0 + wq4);
      #pragma unroll
      for (int ph = 0; ph < 2; ++ph)
        #pragma unroll
        for (int j = 0; j < 4; ++j) {
          uint2 pk;
          pk.x = f2bf2(v[ph][0][j], v[ph][1][j]);
          pk.y = f2bf2(v[ph][2][j], v[ph][3][j]);
          *reinterpret_cast<uint2*>(&sR[(48 + wq4 + j) * WR + cph + 16 * ph]) = pk;
        }
    }
    // ---- stage right margin: window cols 0..47 (= w0-48 .. w0-1);
    // zero-fill for the w0==0 half (block-uniform branch).
    if (tid < 96) {
      const int mw4 = 4 * (tid >> 3);  // 0..44
      const int mc  = 4 * (tid & 7);   // 0..28
      f32x4 v[4];
      if (w0) {
        #pragma unroll
        for (int r = 0; r < 4; ++r)
          v[r] = *reinterpret_cast<const f32x4*>(
              right + bbase + (size_t)(c0 + mc + r) * HWs + (w0 - 48 + mw4));
      } else {
        #pragma unroll
        for (int r = 0; r < 4; ++r) v[r] = (f32x4){0.f, 0.f, 0.f, 0.f};
      }
      #pragma unroll
      for (int j = 0; j < 4; ++j) {
        uint2 pk;
        pk.x = f2bf2(v[0][j], v[1][j]);
        pk.y = f2bf2(v[2][j], v[3][j]);
        *reinterpret_cast<uint2*>(&sR[(mw4 + j) * WR + mc]) = pk;
      }
    }
    __syncthreads();

    // ---- compute: A[m][k] = L[k][u0+m], B[k][n] = R[k][u0+16t+n].
    // One ds_read_b128 per fragment: 8 consecutive c at w = u0+n16,
    // c-block 8q. All offsets fold to immediates off one base VGPR.
    const int rb = (16 * wv + n16) * WR + 8 * q;
    #pragma unroll
    for (int i = 0; i < 4; ++i) {
      const bf16x8 A = *reinterpret_cast<const bf16x8*>(&sL[rb + i * 64 * WR]);
      #pragma unroll
      for (int t = 0; t < 4; ++t) {
        const bf16x8 Bv = *reinterpret_cast<const bf16x8*>(
            &sR[rb + (i * 64 + t * 16) * WR]);
        acc[i][t] =
            __builtin_amdgcn_mfma_f32_16x16x32_bf16(A, Bv, acc[i][t], 0, 0, 0);
      }
    }
    __syncthreads();  // next chunk (or epilogue scratch) reuses LDS
  }

  // ---- epilogue (round-3 verified): block-wide scratch, 2 halves x 24 d-rows
  const float scale = 1.0f / 64.0f;
  #pragma unroll 1
  for (int half = 0; half < 2; ++half) {
    const int dbase = 24 * half;
    if (half) __syncthreads();   // half-0 E2 reads done before overwrite
    // E1: scatter acc -> scr[d - dbase][u0 + m]
    #pragma unroll
    for (int i = 0; i < 4; ++i) {
      const int u0 = (wv + 4 * i) * 16;
      #pragma unroll
      for (int t = 0; t < 4; ++t)
        #pragma unroll
        for (int r = 0; r < 4; ++r) {
          const int m = 4 * q + r;
          const int d = m - n16 + 48 - 16 * t;
          const unsigned int dr = (unsigned int)(d - dbase);
          if (dr < 24u) scr[dr * ST + u0 + m] = acc[i][t][r] * scale;
        }
    }
    __syncthreads();
    // E2: cooperative full-line stores: 24 rows x 64 float4, non-temporal
    const size_t obase = (((size_t)b * DD + dbase) * HH + h) * WW + w0;
    #pragma unroll
    for (int s6 = 0; s6 < 6; ++s6) {
      const int s  = tid + s6 * NT;
      const int dr = s >> 6;
      const int p  = s & 63;
      const f32x4 v = *reinterpret_cast<const f32x4*>(&scr[dr * ST + 4 * p]);
      __builtin_nontemporal_store(
          v, reinterpret_cast<f32x4*>(out + obase + (size_t)dr * HWs + 4 * p));
    }
  }
}

extern "C" void kernel_launch(void* const* d_in, const int* in_sizes, int n_in,
                              void* d_out, int out_size, void* d_ws, size_t ws_size,
                              hipStream_t stream) {
  const float* left  = (const float*)d_in[0];
  const float* right = (const float*)d_in[1];
  float* out = (float*)d_out;

  dim3 grid(WW / TW, HH, BB);   // 2 x 256 x 4 = 2048 blocks
  dim3 block(NT);
  cost_volume_mfma<<<grid, block, 0, stream>>>(left, right, out);
}